// Round 6
// baseline (238.292 us; speedup 1.0000x reference)
//
#include <hip/hip_runtime.h>

// KMEANS encode+decode: B=65536, G=256, K=512, fp32.
// R6: fp16-split MFMA GEMM ranking on s = m2 - 2*xm. Chains kept: xh*mh +
// xh*ml (dropped xl*mh ~ 1.7e-4 std, xl*ml ~ 1e-7; TAU=2e-3 rescue margin
// >= 6 sigma). Wave = 64 rows x 64 codes (acc 64 regs) x 2 code-halves;
// waves_per_eu(3). A staged to LDS in fragment order (coalesced HBM read).
// Rows with best/2nd gap < TAU re-solved exactly in R1 fp32 order (proven
// absmax 0.0 R1-R5). 3 dispatches: prep, gemm(+recon), rescue.

constexpr int BATCH = 65536;
constexpr int GDIM  = 256;   // GEMM K (features)
constexpr int KDIM  = 512;   // GEMM N (codes)
constexpr float TAU = 2e-3f;

typedef _Float16 halfx8 __attribute__((ext_vector_type(8)));
typedef _Float16 halfx4 __attribute__((ext_vector_type(4)));
typedef float    floatx4 __attribute__((ext_vector_type(4)));

// ---------------- prep: transpose + m2 (serial order) + fp16 h/l pack ----
// Pack layout (verified R4/R5): vec (nfg*8 + p)*64 + lane holds 8 halves
// (k = p*32 + (lane>>4)*8 + j) of code column n = nfg*16 + (lane&15).

__global__ __launch_bounds__(256)
void prep_kernel(const float* __restrict__ mu, float* __restrict__ muT,
                 float* __restrict__ m2, halfx8* __restrict__ packh,
                 halfx8* __restrict__ packl, int* __restrict__ rcount) {
    __shared__ float col[GDIM];
    const int k = blockIdx.x;      // code 0..511
    const int g = threadIdx.x;     // feature 0..255
    if (k == 0 && g == 0) *rcount = 0;
    const float v = mu[(size_t)g * KDIM + k];
    muT[(size_t)k * GDIM + g] = v;           // coalesced write
    col[g] = v;
    __syncthreads();
    if (g == 0) {                            // serial g-ascending m2 (proven order)
        float s = 0.f;
        for (int gg = 0; gg < GDIM; ++gg) s += col[gg] * col[gg];
        m2[k] = s;
    }
    if (g < 32) {                            // 32 chunks of 8 halves
        const int p = g >> 2, q = g & 3;
        const int k0 = p * 32 + q * 8;
        halfx8 hv, lv;
        #pragma unroll
        for (int j = 0; j < 8; ++j) {
            const float x = col[k0 + j];
            const _Float16 h = (_Float16)x;
            hv[j] = h;
            lv[j] = (_Float16)(x - (float)h);
        }
        const int nf = k >> 4, n15 = k & 15;
        const int idx = ((nf * 8 + p) * 4 + q) * 16 + n15;
        packh[idx] = hv;
        packl[idx] = lv;
    }
}

// ---------------- main MFMA GEMM + argmin + fused recon ----------------

__global__ __launch_bounds__(256) __attribute__((amdgpu_waves_per_eu(3)))
void gemm_argmin_mfma(const float* __restrict__ images,
                      const halfx8* __restrict__ packh,
                      const halfx8* __restrict__ packl,
                      const float* __restrict__ m2g,
                      const float* __restrict__ muT,
                      float* __restrict__ out,
                      int* __restrict__ rlist, int* __restrict__ rcount) {
    __shared__ _Float16 Ash[4 * 8 * 64 * 8];   // 16384 halves = 32 KB, frag order
    __shared__ float sd1[4][64];
    __shared__ float sd2[4][64];
    __shared__ int   sk1[4][64];
    __shared__ int   kb[64];

    const int tid  = threadIdx.x;
    const int wave = tid >> 6;
    const int lane = tid & 63;
    const int q    = lane >> 4;
    const int l15  = lane & 15;
    const int m0   = blockIdx.x * 64;

    // ---- stage A (hi half only) into LDS in fragment-read order ----
    {
        const float4* img4 = (const float4*)images;
        #pragma unroll
        for (int i = 0; i < 16; ++i) {
            const int idx = tid + i * 256;          // 0..4095
            const int row = idx >> 6, c4 = idx & 63;
            const float4 v = img4[(size_t)m0 * 64 + idx];   // coalesced
            const int chunk = c4 >> 1, hi = c4 & 1;
            const int mf = row >> 4, rl = row & 15;
            const int pp = chunk >> 2, qq = chunk & 3;
            halfx4 h4;
            h4[0] = (_Float16)v.x; h4[1] = (_Float16)v.y;
            h4[2] = (_Float16)v.z; h4[3] = (_Float16)v.w;
            *(halfx4*)&Ash[(((mf * 8 + pp) * 64 + qq * 16 + rl) * 8) + hi * 4] = h4;
        }
    }
    __syncthreads();

    // persistent best/2nd-best per (mf,r) across both code-halves
    float d1[4][4], d2[4][4];
    int   k1[4][4];
    #pragma unroll
    for (int mf = 0; mf < 4; ++mf)
        #pragma unroll
        for (int r = 0; r < 4; ++r) { d1[mf][r] = 3.402823466e+38f; d2[mf][r] = 3.402823466e+38f; k1[mf][r] = 0; }

    for (int half = 0; half < 2; ++half) {
        floatx4 acc[4][4] = {};
        const int nbase = half * 16 + wave * 4;     // nf-group base (16 codes each)

        #pragma unroll 2
        for (int p = 0; p < 8; ++p) {
            halfx8 Ah[4];
            #pragma unroll
            for (int mf = 0; mf < 4; ++mf)
                Ah[mf] = *(const halfx8*)&Ash[((mf * 8 + p) * 64 + lane) * 8];
            #pragma unroll
            for (int nf = 0; nf < 4; ++nf) {
                const int bidx = ((nbase + nf) * 8 + p) * 64 + lane;
                const halfx8 Bh = packh[bidx];
                const halfx8 Bl = packl[bidx];
                #pragma unroll
                for (int mf = 0; mf < 4; ++mf) {
                    acc[mf][nf] = __builtin_amdgcn_mfma_f32_16x16x32_f16(Ah[mf], Bh, acc[mf][nf], 0, 0, 0);
                    acc[mf][nf] = __builtin_amdgcn_mfma_f32_16x16x32_f16(Ah[mf], Bl, acc[mf][nf], 0, 0, 0);
                }
            }
        }

        // epilogue for this half; ascending (half, nf) = ascending k per lane
        #pragma unroll
        for (int nf = 0; nf < 4; ++nf) {
            const int kc = (nbase + nf) * 16 + l15;
            const float m2v = m2g[kc];
            #pragma unroll
            for (int mf = 0; mf < 4; ++mf)
                #pragma unroll
                for (int r = 0; r < 4; ++r) {
                    const float d = m2v - 2.0f * acc[mf][nf][r];
                    if (d < d1[mf][r]) { d2[mf][r] = d1[mf][r]; d1[mf][r] = d; k1[mf][r] = kc; }
                    else if (d < d2[mf][r]) { d2[mf][r] = d; }
                }
        }
    }

    // butterfly across 16 lanes of each quad; lexicographic (d,k) tie-break
    #pragma unroll
    for (int s = 1; s < 16; s <<= 1) {
        #pragma unroll
        for (int mf = 0; mf < 4; ++mf)
            #pragma unroll
            for (int r = 0; r < 4; ++r) {
                const float od1 = __shfl_xor(d1[mf][r], s, 64);
                const int   ok1 = __shfl_xor(k1[mf][r], s, 64);
                const float od2 = __shfl_xor(d2[mf][r], s, 64);
                const bool take = (od1 < d1[mf][r]) || (od1 == d1[mf][r] && ok1 < k1[mf][r]);
                const float loser = take ? d1[mf][r] : od1;
                if (take) { d1[mf][r] = od1; k1[mf][r] = ok1; }
                const float m2x = (od2 < d2[mf][r]) ? od2 : d2[mf][r];
                d2[mf][r] = (loser < m2x) ? loser : m2x;
            }
    }

    if (l15 == 0) {
        #pragma unroll
        for (int mf = 0; mf < 4; ++mf)
            #pragma unroll
            for (int r = 0; r < 4; ++r) {
                const int ml = mf * 16 + q * 4 + r;
                sd1[wave][ml] = d1[mf][r];
                sd2[wave][ml] = d2[mf][r];
                sk1[wave][ml] = k1[mf][r];
            }
    }
    __syncthreads();

    if (tid < 64) {
        float D1 = sd1[0][tid], D2 = sd2[0][tid];
        int   K1 = sk1[0][tid];
        #pragma unroll
        for (int w = 1; w < 4; ++w) {   // lexicographic (waves not k-ordered)
            const float od1 = sd1[w][tid], od2 = sd2[w][tid];
            const int   ok1 = sk1[w][tid];
            if (od1 < D1 || (od1 == D1 && ok1 < K1)) {
                D2 = (D1 < od2) ? D1 : od2; D1 = od1; K1 = ok1;
            } else {
                D2 = (od1 < D2) ? od1 : D2;
            }
        }
        kb[tid] = K1;
        if (D2 - D1 < TAU) {
            const int i = atomicAdd(rcount, 1);
            rlist[i] = m0 + tid;
        }
    }
    __syncthreads();

    // ---- fused recon from muT (L2-hot) ----
    float4* out4 = (float4*)(out + (size_t)m0 * GDIM);
    const float4* muT4 = (const float4*)muT;
    #pragma unroll
    for (int i = 0; i < 16; ++i) {
        const int idx = tid + i * 256;
        const int rr = idx >> 6, cc = idx & 63;
        out4[idx] = muT4[(size_t)kb[rr] * (GDIM / 4) + cc];
    }
}

// ---------------- rescue: exact R1-order fp32 recompute + recon ----------

__global__ __launch_bounds__(256)
void rescue_kernel(const float* __restrict__ images, const float* __restrict__ mu,
                   const float* __restrict__ m2g, const float* __restrict__ muT,
                   const int* __restrict__ rlist, const int* __restrict__ rcount,
                   float* __restrict__ out) {
    __shared__ float xs[GDIM];
    __shared__ float sd[256];
    __shared__ int   sk[256];
    const int tid = threadIdx.x;
    const int cnt = *rcount;
    for (int i = blockIdx.x; i < cnt; i += gridDim.x) {
        const int row = rlist[i];
        xs[tid] = images[(size_t)row * GDIM + tid];
        __syncthreads();
        float x2 = 0.f;
        for (int g = 0; g < GDIM; ++g) x2 += xs[g] * xs[g];
        float sA = 0.f, sB = 0.f;
        for (int g = 0; g < GDIM; ++g) {
            const float xv = xs[g];
            const float* mp = mu + (size_t)g * KDIM;
            sA += xv * mp[tid];
            sB += xv * mp[tid + 256];
        }
        const float dA = (x2 - 2.0f * sA) + m2g[tid];
        const float dB = (x2 - 2.0f * sB) + m2g[tid + 256];
        float bd = dA; int bk = tid;
        if (dB < bd) { bd = dB; bk = tid + 256; }
        sd[tid] = bd; sk[tid] = bk;
        __syncthreads();
        for (int s = 128; s > 0; s >>= 1) {
            if (tid < s) {
                const float db = sd[tid + s]; const int kb2 = sk[tid + s];
                if (db < sd[tid] || (db == sd[tid] && kb2 < sk[tid])) { sd[tid] = db; sk[tid] = kb2; }
            }
            __syncthreads();
        }
        const int kwin = sk[0];
        out[(size_t)row * GDIM + tid] = muT[(size_t)kwin * GDIM + tid];
        __syncthreads();
    }
}

// ---------------- fallback (R1 kernel, no workspace) ----------------

constexpr int FROWS = 64, FXSTR = GDIM + 1;

__global__ __launch_bounds__(256)
void kmeans_fallback(const float* __restrict__ images, const float* __restrict__ mu,
                     float* __restrict__ out) {
    __shared__ float xs[FROWS * FXSTR];
    __shared__ float m2s[KDIM];
    __shared__ float bd_s[4][FROWS];
    __shared__ int   bk_s[4][FROWS];
    __shared__ int   kbest_s[FROWS];
    const int tid = threadIdx.x;
    const long long b0 = (long long)blockIdx.x * FROWS;
    {
        const float4* img4 = (const float4*)(images + b0 * GDIM);
        #pragma unroll
        for (int i = 0; i < 16; ++i) {
            const int idx = tid + i * 256;
            const int r = idx >> 6, c = idx & 63;
            const float4 v = img4[idx];
            float* dst = &xs[r * FXSTR + c * 4];
            dst[0] = v.x; dst[1] = v.y; dst[2] = v.z; dst[3] = v.w;
        }
    }
    {
        float s0 = 0.f, s1 = 0.f;
        for (int g = 0; g < GDIM; ++g) {
            const float a = mu[(size_t)g * KDIM + tid];
            const float b = mu[(size_t)g * KDIM + tid + 256];
            s0 += a * a; s1 += b * b;
        }
        m2s[tid] = s0; m2s[tid + 256] = s1;
    }
    __syncthreads();
    const int r = tid & (FROWS - 1), ch = tid >> 6;
    const float* xrow = &xs[r * FXSTR];
    float x2 = 0.f;
    #pragma unroll 8
    for (int g = 0; g < GDIM; ++g) x2 += xrow[g] * xrow[g];
    float bestd = 3.402823466e+38f; int bestk = 0;
    const int k0base = ch * (KDIM / 4);
    for (int kt = 0; kt < KDIM / 4; kt += 8) {
        const int k0 = k0base + kt;
        float a8[8];
        #pragma unroll
        for (int j = 0; j < 8; ++j) a8[j] = 0.f;
        const float* mp = mu + k0;
        #pragma unroll 4
        for (int g = 0; g < GDIM; ++g) {
            const float xv = xrow[g];
            const float4 a = *(const float4*)(mp + (size_t)g * KDIM);
            const float4 b = *(const float4*)(mp + (size_t)g * KDIM + 4);
            a8[0] += xv * a.x; a8[1] += xv * a.y; a8[2] += xv * a.z; a8[3] += xv * a.w;
            a8[4] += xv * b.x; a8[5] += xv * b.y; a8[6] += xv * b.z; a8[7] += xv * b.w;
        }
        #pragma unroll
        for (int j = 0; j < 8; ++j) {
            const float t = x2 - 2.0f * a8[j];
            const float d = t + m2s[k0 + j];
            if (d < bestd) { bestd = d; bestk = k0 + j; }
        }
    }
    bd_s[ch][r] = bestd; bk_s[ch][r] = bestk;
    __syncthreads();
    if (tid < FROWS) {
        float bd = bd_s[0][tid]; int bk = bk_s[0][tid];
        #pragma unroll
        for (int c = 1; c < 4; ++c)
            if (bd_s[c][tid] < bd) { bd = bd_s[c][tid]; bk = bk_s[c][tid]; }
        kbest_s[tid] = bk;
    }
    __syncthreads();
    for (int i = tid; i < FROWS * GDIM; i += 256) {
        const int rr = i >> 8, gg = i & (GDIM - 1);
        out[b0 * GDIM + i] = mu[(size_t)gg * KDIM + kbest_s[rr]];
    }
}

// ---------------- launch ----------------

extern "C" void kernel_launch(void* const* d_in, const int* in_sizes, int n_in,
                              void* d_out, int out_size, void* d_ws, size_t ws_size,
                              hipStream_t stream) {
    const float* images = (const float*)d_in[0];
    const float* mu     = (const float*)d_in[1];
    float* out = (float*)d_out;

    float* ws    = (float*)d_ws;
    float* muT   = ws;                          // 131072 floats
    float* m2    = ws + 131072;                 // 512
    halfx8* packh = (halfx8*)(ws + 131584);     // 65536 floats (16384 vecs)
    halfx8* packl = (halfx8*)(ws + 197120);     // 65536 floats
    int*   rlist = (int*)(ws + 262656);         // 65536
    int*   rcount = (int*)(ws + 328192);        // 16
    const size_t need = (size_t)328208 * sizeof(float);

    if (d_ws != nullptr && ws_size >= need) {
        prep_kernel<<<KDIM, GDIM, 0, stream>>>(mu, muT, m2, packh, packl, rcount);
        gemm_argmin_mfma<<<BATCH / 64, 256, 0, stream>>>(images, packh, packl,
                                                         m2, muT, out, rlist, rcount);
        rescue_kernel<<<1024, 256, 0, stream>>>(images, mu, m2, muT, rlist, rcount, out);
    } else {
        kmeans_fallback<<<BATCH / 64, 256, 0, stream>>>(images, mu, out);
    }
}